// Round 4
// baseline (3838.823 us; speedup 1.0000x reference)
//
#include <hip/hip_runtime.h>

// NeuralCDE RK4 — R9: R7 structure (3 barriers/stage — R8's barrier removal
// regressed and is reverted) + register-pressure fix:
//   1. __launch_bounds__(WG, 1): R7's (WG,2) capped the allocator at 128 VGPRs
//      while persistent fragment state needs ~230 -> ~108 regs spilled/thread
//      (WRITE_SIZE 55 MB =~ 433 B/thread of scratch stores; reloads every
//      stage). Lifting the cap keeps demand <= 256 -> still 2 waves/SIMD
//      (occupancy is grid-limited at 8 waves/CU: 512 WGs / 256 CUs).
//   2. RK4 state (za, zb) in registers with R7's fixed thread->(b,o) map
//      (sZa/sZb LDS arrays deleted; no sync change).
//   3. v_cvt_pk_bf16_f32 packed bf16 conversion (RNE, bit-identical to f2bf)
//      in the h-split and z-split epilogues: ~60 fewer VALU inst/thread/stage.
// Arithmetic order unchanged -> bit-identical output (absmax 0.0).
// MFMA conventions = HW-verified m89/m120 mappings:
//   A[m=lane&15][k=quad*8+j], B[k=quad*8+j][n=lane&15], D[row=quad*4+r][col=lane&15]

typedef short short8  __attribute__((ext_vector_type(8)));
typedef float floatx4 __attribute__((ext_vector_type(4)));

constexpr int B_TOT  = 8192;
constexpr int L      = 256;
constexpr int CIN    = 6;
constexpr int H      = 32;
constexpr int MID    = 128;
constexpr int NSTEPS = L - 1;   // 255
constexpr int NB     = 16;      // batches per WG (one 16-row M tile)
constexpr int WG     = 256;     // 4 waves
// grid = B_TOT/NB = 512 -> 2 blocks/CU

constexpr int HP  = 152;   // h split row stride (shorts): 76 dw === 12 mod 32
constexpr int ZSP = 72;    // z split row stride (shorts): 36 dw === 4 mod 32
constexpr int GIS = 33;    // sG i-stride (floats)
constexpr int GBS = 199;   // sG batch-stride (floats)
constexpr int ZP  = 33;    // final-state rows (odd)

__device__ __forceinline__ short f2bf(float x) {     // RNE fp32 -> bf16 bits
    unsigned u = __builtin_bit_cast(unsigned, x);
    unsigned r = (u + 0x7FFFu + ((u >> 16) & 1u)) >> 16;
    return (short)r;
}
__device__ __forceinline__ float bf2f(short b) {
    unsigned u = ((unsigned)(unsigned short)b) << 16;
    return __builtin_bit_cast(float, u);
}
// packed RNE conversion: dst = {lo16: bf16(a), hi16: bf16(b)}
__device__ __forceinline__ unsigned cvt_pk_bf16(float a, float b) {
    unsigned r;
    asm("v_cvt_pk_bf16_f32 %0, %1, %2" : "=v"(r) : "v"(a), "v"(b));
    return r;
}
__device__ __forceinline__ float lo_bf(unsigned p) {
    return __builtin_bit_cast(float, p << 16);
}
__device__ __forceinline__ float hi_bf(unsigned p) {
    return __builtin_bit_cast(float, p & 0xFFFF0000u);
}

__global__ __launch_bounds__(WG, 1)
void cde_hybrid_kernel(const float* __restrict__ times,
                       const float* __restrict__ coeff_b,
                       const float* __restrict__ coeff_c,
                       const float* __restrict__ coeff_d,
                       const float* __restrict__ W1g,
                       const float* __restrict__ b1g,
                       const float* __restrict__ W2g,
                       const float* __restrict__ b2g,
                       const float* __restrict__ Wlg,
                       const float* __restrict__ blg,
                       float* __restrict__ out)
{
    __shared__ __align__(16) short sHh[NB][HP], sHm[NB][HP], sHl[NB][HP]; // 14.25 KB
    __shared__ float sGf[NB * GBS + 4];                                   // 12.75 KB
    __shared__ __align__(16) short sZh[NB][ZSP], sZm[NB][ZSP], sZl[NB][ZSP]; // 6.75 KB
    __shared__ float sDx[3][NB][8];                                       // 1.5 KB
    __shared__ float sFin[NB][ZP];                                        // 2.1 KB

    const int tid  = threadIdx.x;
    const int lane = tid & 63;
    const int wave = tid >> 6;      // 0..3
    const int l15  = lane & 15;
    const int q    = lane >> 4;     // 0..3
    const int b0   = blockIdx.x * NB;

    // ---- one-time: W2 fragments -> registers (bf16 hi/mid/lo), phase-2 B ----
    short8 w2h[3][4], w2m[3][4], w2l[3][4];
    float  b2v[3];
    int    gofs[3];                 // precomputed (n%6)*GIS + n/6 for sG stores
    #pragma unroll
    for (int f = 0; f < 3; ++f) {
        const int n = (wave * 3 + f) * 16 + l15;
        b2v[f]  = b2g[n];
        gofs[f] = (n % 6) * GIS + (n / 6);
        #pragma unroll
        for (int ks = 0; ks < 4; ++ks) {
            #pragma unroll
            for (int j = 0; j < 8; ++j) {
                const float w = W2g[(ks * 32 + q * 8 + j) * (H * CIN) + n];
                const short hh = f2bf(w);        const float r1 = w - bf2f(hh);
                const short mm = f2bf(r1);       const float r2 = r1 - bf2f(mm);
                w2h[f][ks][j] = hh; w2m[f][ks][j] = mm; w2l[f][ks][j] = f2bf(r2);
            }
        }
    }

    // ---- one-time: W1^T fragments -> registers (bf16 hi/mid/lo), phase-1 A ----
    short8 w1h[2], w1m[2], w1l[2];
    float  b1v[2][4];
    #pragma unroll
    for (int f1 = 0; f1 < 2; ++f1) {
        const int mt = wave * 2 + f1;
        #pragma unroll
        for (int j = 0; j < 8; ++j) {
            const float w = W1g[(q * 8 + j) * MID + mt * 16 + l15];
            const short hh = f2bf(w);        const float r1 = w - bf2f(hh);
            const short mm = f2bf(r1);       const float r2 = r1 - bf2f(mm);
            w1h[f1][j] = hh; w1m[f1][j] = mm; w1l[f1][j] = f2bf(r2);
        }
        #pragma unroll
        for (int r = 0; r < 4; ++r)
            b1v[f1][r] = b1g[mt * 16 + q * 4 + r];   // D row = mid = mt*16+q*4+r
    }

    // ---- one-time init: z splits to zero; RK4 state in registers ----
    // thread owns (b,o) pairs: pp = tid + 256*jj -> b = pp>>5, o = pp&31
    float za[2] = {0.f, 0.f};
    float zb[2] = {0.f, 0.f};
    for (int i = tid; i < NB * ZSP; i += WG) {
        (&sZh[0][0])[i] = 0; (&sZm[0][0])[i] = 0; (&sZl[0][0])[i] = 0;
    }
    __syncthreads();

    for (int t = 0; t < NSTEPS; ++t) {
        const float dt = times[t + 1] - times[t];
        if (tid < NB * CIN) {
            const int bb = tid / CIN, ii = tid - bb * CIN;
            const size_t off = ((size_t)(b0 + bb) * NSTEPS + t) * CIN + ii;
            const float vb = coeff_b[off], vc = coeff_c[off], vd = coeff_d[off];
            const float f1 = 0.5f * dt;
            sDx[0][bb][ii] = vb;                              // dX(0)
            sDx[1][bb][ii] = vb + vc * f1 + vd * f1 * f1;     // dX(dt/2)
            sDx[2][bb][ii] = vb + vc * dt + vd * dt * dt;     // dX(dt)
        }
        __syncthreads();

        #pragma unroll 1
        for (int s = 0; s < 4; ++s) {
            // ---------- phase 1 (MFMA): h^T = tanh(W1^T @ z^T + b1) ----------
            const short8 zh = *(const short8*)&sZh[l15][q * 8];
            const short8 zm = *(const short8*)&sZm[l15][q * 8];
            const short8 zl = *(const short8*)&sZl[l15][q * 8];
            floatx4 ht[2];
            #pragma unroll
            for (int f1 = 0; f1 < 2; ++f1) ht[f1] = floatx4{0.f, 0.f, 0.f, 0.f};
            #pragma unroll
            for (int f1 = 0; f1 < 2; ++f1) {
                ht[f1] = __builtin_amdgcn_mfma_f32_16x16x32_bf16(w1h[f1], zh, ht[f1], 0, 0, 0);
                ht[f1] = __builtin_amdgcn_mfma_f32_16x16x32_bf16(w1h[f1], zm, ht[f1], 0, 0, 0);
                ht[f1] = __builtin_amdgcn_mfma_f32_16x16x32_bf16(w1m[f1], zh, ht[f1], 0, 0, 0);
                ht[f1] = __builtin_amdgcn_mfma_f32_16x16x32_bf16(w1h[f1], zl, ht[f1], 0, 0, 0);
                ht[f1] = __builtin_amdgcn_mfma_f32_16x16x32_bf16(w1m[f1], zm, ht[f1], 0, 0, 0);
                ht[f1] = __builtin_amdgcn_mfma_f32_16x16x32_bf16(w1l[f1], zh, ht[f1], 0, 0, 0);
            }
            // D[row=q*4+r][col=l15] = h^T[mid=mt*16+q*4+r][batch=l15]
            // bias, tanh, 3-way packed split, b64 store of 4 consecutive mids
            #pragma unroll
            for (int f1 = 0; f1 < 2; ++f1) {
                const int mt = wave * 2 + f1;
                float hv[4];
                #pragma unroll
                for (int r = 0; r < 4; ++r) {
                    const float pre = ht[f1][r] + b1v[f1][r];
                    const float e = __expf(2.f * pre);        // tanh
                    hv[r] = 1.f - 2.f / (e + 1.f);
                }
                const unsigned ph0 = cvt_pk_bf16(hv[0], hv[1]);
                const unsigned ph1 = cvt_pk_bf16(hv[2], hv[3]);
                const float m0 = hv[0] - lo_bf(ph0), m1 = hv[1] - hi_bf(ph0);
                const float m2 = hv[2] - lo_bf(ph1), m3 = hv[3] - hi_bf(ph1);
                const unsigned pm0 = cvt_pk_bf16(m0, m1);
                const unsigned pm1 = cvt_pk_bf16(m2, m3);
                const float l0 = m0 - lo_bf(pm0), l1 = m1 - hi_bf(pm0);
                const float l2 = m2 - lo_bf(pm1), l3 = m3 - hi_bf(pm1);
                const unsigned pl0 = cvt_pk_bf16(l0, l1);
                const unsigned pl1 = cvt_pk_bf16(l2, l3);
                *(uint2*)&sHh[l15][mt * 16 + q * 4] = uint2{ph0, ph1};
                *(uint2*)&sHm[l15][mt * 16 + q * 4] = uint2{pm0, pm1};
                *(uint2*)&sHl[l15][mt * 16 + q * 4] = uint2{pl0, pl1};
            }
            __syncthreads();

            // ---------- phase 2 (MFMA): G = h @ W2 + b2, K=128 ----------
            floatx4 g[3];
            #pragma unroll
            for (int f = 0; f < 3; ++f) g[f] = floatx4{0.f, 0.f, 0.f, 0.f};
            #pragma unroll
            for (int ks = 0; ks < 4; ++ks) {
                const short8 ah = *(const short8*)&sHh[l15][ks * 32 + q * 8];
                const short8 am = *(const short8*)&sHm[l15][ks * 32 + q * 8];
                const short8 al = *(const short8*)&sHl[l15][ks * 32 + q * 8];
                #pragma unroll
                for (int f = 0; f < 3; ++f) {
                    g[f] = __builtin_amdgcn_mfma_f32_16x16x32_bf16(ah, w2h[f][ks], g[f], 0, 0, 0);
                    g[f] = __builtin_amdgcn_mfma_f32_16x16x32_bf16(ah, w2m[f][ks], g[f], 0, 0, 0);
                    g[f] = __builtin_amdgcn_mfma_f32_16x16x32_bf16(am, w2h[f][ks], g[f], 0, 0, 0);
                    g[f] = __builtin_amdgcn_mfma_f32_16x16x32_bf16(ah, w2l[f][ks], g[f], 0, 0, 0);
                    g[f] = __builtin_amdgcn_mfma_f32_16x16x32_bf16(am, w2m[f][ks], g[f], 0, 0, 0);
                    g[f] = __builtin_amdgcn_mfma_f32_16x16x32_bf16(al, w2h[f][ks], g[f], 0, 0, 0);
                }
            }
            // store in [b][i*GIS+o] layout: addr = batch*GBS + (n%6)*GIS + n/6
            #pragma unroll
            for (int f = 0; f < 3; ++f) {
                #pragma unroll
                for (int r = 0; r < 4; ++r)
                    sGf[(q * 4 + r) * GBS + gofs[f]] = g[f][r] + b2v[f];
            }
            __syncthreads();

            // ---------- contraction k = G . dx, RK4 update, packed z-split ----
            const int dsel = (s == 0) ? 0 : ((s == 3) ? 2 : 1);
            const float ws = (s == 0 || s == 3) ? dt * (1.f / 6.f) : dt * (1.f / 3.f);
            const int o  = tid & 31;
            const int bA = tid >> 5, bB = bA + 8;     // jj=0 / jj=1 batches
            float zcv[2];
            #pragma unroll
            for (int jj = 0; jj < 2; ++jj) {
                const int b = (jj == 0) ? bA : bB;
                float k = 0.f;
                #pragma unroll
                for (int i = 0; i < 6; ++i)
                    k += sGf[b * GBS + i * GIS + o] * sDx[dsel][b][i];
                const float zan = za[jj] + ws * k;
                za[jj] = zan;
                if (s < 3) {
                    zcv[jj] = zb[jj] + ((s == 2) ? dt : 0.5f * dt) * k;
                } else {
                    zb[jj] = zan;
                    zcv[jj] = zan;
                }
            }
            // packed 3-way bf16 split of next-stage z (phase-1 B operand)
            const unsigned pzh = cvt_pk_bf16(zcv[0], zcv[1]);
            sZh[bA][o] = (short)pzh; sZh[bB][o] = (short)(pzh >> 16);
            const float zm0 = zcv[0] - lo_bf(pzh), zm1 = zcv[1] - hi_bf(pzh);
            const unsigned pzm = cvt_pk_bf16(zm0, zm1);
            sZm[bA][o] = (short)pzm; sZm[bB][o] = (short)(pzm >> 16);
            const float zl0 = zm0 - lo_bf(pzm), zl1 = zm1 - hi_bf(pzm);
            const unsigned pzl = cvt_pk_bf16(zl0, zl1);
            sZl[bA][o] = (short)pzl; sZl[bB][o] = (short)(pzl >> 16);
            __syncthreads();
        }
    }

    // ---------- readout: out = zT @ Wl + bl ----------
    {
        const int o = tid & 31, bA = tid >> 5;
        sFin[bA][o]     = zb[0];
        sFin[bA + 8][o] = zb[1];
    }
    __syncthreads();
    if (tid < NB * CIN) {
        const int bb = tid / CIN, c = tid - bb * CIN;
        float acc = blg[c];
        #pragma unroll
        for (int o = 0; o < H; ++o) acc += sFin[bb][o] * Wlg[o * CIN + c];
        out[(size_t)(b0 + bb) * CIN + c] = acc;
    }
}

extern "C" void kernel_launch(void* const* d_in, const int* in_sizes, int n_in,
                              void* d_out, int out_size, void* d_ws, size_t ws_size,
                              hipStream_t stream) {
    const float* times = (const float*)d_in[0];
    // d_in[1] = coeff_a: unused by the reference vector field
    const float* cb = (const float*)d_in[2];
    const float* cc = (const float*)d_in[3];
    const float* cd = (const float*)d_in[4];
    const float* W1 = (const float*)d_in[5];
    const float* b1 = (const float*)d_in[6];
    const float* W2 = (const float*)d_in[7];
    const float* b2 = (const float*)d_in[8];
    const float* Wl = (const float*)d_in[9];
    const float* bl = (const float*)d_in[10];
    float* out = (float*)d_out;

    hipLaunchKernelGGL(cde_hybrid_kernel, dim3(B_TOT / NB), dim3(WG), 0, stream,
                       times, cb, cc, cd, W1, b1, W2, b2, Wl, bl, out);
}

// Round 5
// 2294.981 us; speedup vs baseline: 1.6727x; 1.6727x over previous
//
#include <hip/hip_runtime.h>

// NeuralCDE RK4 — R10: fp16 2-way split replaces bf16 3-way split in BOTH
// MFMA phases. fp16 = 11 mantissa bits -> hi + 2^11-scaled residual carries
// ~22 bits (=~fp32); 3 products per tile instead of 6:
//   main acc:   Ah*Bh
//   scaled acc: Ah*Bl' + Al'*Bh   (Al' = fp16((A-Ah)*2^11), always normal)
//   combine:    D = main + scaled * 2^-11   (power-of-2 scale, exact)
// Dropped term Ar*Br ~ 2^-22 rel; per-product err ~3*2^-22 =~ fp32 noise.
// Effects vs R7/R9:
//   - MFMA per wave-stage 84 -> 42
//   - W2 frags 144 -> 96 VGPRs, W1 24 -> 16: total demand ~210 <= 256
//     -> no spills AND 2 blocks/CU at __launch_bounds__(WG,1)
//   - split LDS arrays 3 -> 2 per operand (less traffic + conversion VALU)
// R9's inline-asm cvt_pk REMOVED (m240: -37%); scalar casts only.
// Structure = R7 (3 barriers/stage); za/zb RK4 state in registers (R9, kept).
// MFMA conventions = HW-verified m89/m120 mappings:
//   A[m=lane&15][k=quad*8+j], B[k=quad*8+j][n=lane&15], D[row=quad*4+r][col=lane&15]

typedef _Float16 half8 __attribute__((ext_vector_type(8)));
typedef _Float16 half4 __attribute__((ext_vector_type(4)));
typedef float floatx4 __attribute__((ext_vector_type(4)));

constexpr int B_TOT  = 8192;
constexpr int L      = 256;
constexpr int CIN    = 6;
constexpr int H      = 32;
constexpr int MID    = 128;
constexpr int NSTEPS = L - 1;   // 255
constexpr int NB     = 16;      // batches per WG (one 16-row M tile)
constexpr int WG     = 256;     // 4 waves
// grid = B_TOT/NB = 512 -> 2 blocks/CU

constexpr int HP  = 152;   // h split row stride (halves): 76 dw === 12 mod 32
constexpr int ZSP = 72;    // z split row stride (halves): 36 dw === 4 mod 32
constexpr int GIS = 33;    // sG i-stride (floats)
constexpr int GBS = 199;   // sG batch-stride (floats)
constexpr int ZP  = 33;    // final-state rows (odd)

constexpr float RSC  = 2048.f;        // 2^11 residual scale
constexpr float IRSC = 1.f / 2048.f;  // exact power of 2

__global__ __launch_bounds__(WG, 1)
void cde_hybrid_kernel(const float* __restrict__ times,
                       const float* __restrict__ coeff_b,
                       const float* __restrict__ coeff_c,
                       const float* __restrict__ coeff_d,
                       const float* __restrict__ W1g,
                       const float* __restrict__ b1g,
                       const float* __restrict__ W2g,
                       const float* __restrict__ b2g,
                       const float* __restrict__ Wlg,
                       const float* __restrict__ blg,
                       float* __restrict__ out)
{
    __shared__ __align__(16) _Float16 sHh[NB][HP], sHl[NB][HP];   // 9.5 KB
    __shared__ float sGf[NB * GBS + 4];                           // 12.75 KB
    __shared__ __align__(16) _Float16 sZh[NB][ZSP], sZl[NB][ZSP]; // 4.5 KB
    __shared__ float sDx[3][NB][8];                               // 1.5 KB
    __shared__ float sFin[NB][ZP];                                // 2.1 KB

    const int tid  = threadIdx.x;
    const int lane = tid & 63;
    const int wave = tid >> 6;      // 0..3
    const int l15  = lane & 15;
    const int q    = lane >> 4;     // 0..3
    const int b0   = blockIdx.x * NB;

    // ---- one-time: W2 fragments -> registers (fp16 hi + scaled-res), phase-2 B ----
    // wave covers N-tiles {3*wave .. 3*wave+2}; K covered by ks=0..3.
    half8 w2h[3][4], w2l[3][4];
    float b2v[3];
    int   gofs[3];                  // precomputed (n%6)*GIS + n/6 for sG stores
    #pragma unroll
    for (int f = 0; f < 3; ++f) {
        const int n = (wave * 3 + f) * 16 + l15;
        b2v[f]  = b2g[n];
        gofs[f] = (n % 6) * GIS + (n / 6);
        #pragma unroll
        for (int ks = 0; ks < 4; ++ks) {
            #pragma unroll
            for (int j = 0; j < 8; ++j) {
                const float w = W2g[(ks * 32 + q * 8 + j) * (H * CIN) + n];
                const _Float16 hh = (_Float16)w;
                w2h[f][ks][j] = hh;
                w2l[f][ks][j] = (_Float16)((w - (float)hh) * RSC);
            }
        }
    }

    // ---- one-time: W1^T fragments -> registers (fp16 hi + scaled-res), phase-1 A ----
    // wave covers mid-tiles {2*wave, 2*wave+1}; K=H=32 in one MFMA pass.
    // A[m=l15][k=q*8+j] = W1^T[mt*16+l15][k] = W1[k][mt*16+l15]
    half8 w1h[2], w1l[2];
    float b1v[2][4];
    #pragma unroll
    for (int f1 = 0; f1 < 2; ++f1) {
        const int mt = wave * 2 + f1;
        #pragma unroll
        for (int j = 0; j < 8; ++j) {
            const float w = W1g[(q * 8 + j) * MID + mt * 16 + l15];
            const _Float16 hh = (_Float16)w;
            w1h[f1][j] = hh;
            w1l[f1][j] = (_Float16)((w - (float)hh) * RSC);
        }
        #pragma unroll
        for (int r = 0; r < 4; ++r)
            b1v[f1][r] = b1g[mt * 16 + q * 4 + r];   // D row = mid = mt*16+q*4+r
    }

    // ---- one-time init: z splits to zero; RK4 state in registers ----
    // thread owns (b,o): o = tid&31, batches bA = tid>>5 and bB = bA+8
    float za[2] = {0.f, 0.f};
    float zb[2] = {0.f, 0.f};
    for (int i = tid; i < NB * ZSP; i += WG) {
        (&sZh[0][0])[i] = (_Float16)0.f; (&sZl[0][0])[i] = (_Float16)0.f;
    }
    __syncthreads();

    for (int t = 0; t < NSTEPS; ++t) {
        const float dt = times[t + 1] - times[t];
        if (tid < NB * CIN) {
            const int bb = tid / CIN, ii = tid - bb * CIN;
            const size_t off = ((size_t)(b0 + bb) * NSTEPS + t) * CIN + ii;
            const float vb = coeff_b[off], vc = coeff_c[off], vd = coeff_d[off];
            const float f1 = 0.5f * dt;
            sDx[0][bb][ii] = vb;                              // dX(0)
            sDx[1][bb][ii] = vb + vc * f1 + vd * f1 * f1;     // dX(dt/2)
            sDx[2][bb][ii] = vb + vc * dt + vd * dt * dt;     // dX(dt)
        }
        __syncthreads();

        #pragma unroll 1
        for (int s = 0; s < 4; ++s) {
            // ---------- phase 1 (MFMA): h^T = tanh(W1^T @ z^T + b1) ----------
            // B-frag: B[k=q*8+j][n=l15] = z[l15][q*8+j]  (b128 row read)
            const half8 zh = *(const half8*)&sZh[l15][q * 8];
            const half8 zl = *(const half8*)&sZl[l15][q * 8];
            floatx4 ht[2], htr[2];
            #pragma unroll
            for (int f1 = 0; f1 < 2; ++f1) {
                ht[f1]  = floatx4{0.f, 0.f, 0.f, 0.f};
                htr[f1] = floatx4{0.f, 0.f, 0.f, 0.f};
            }
            #pragma unroll
            for (int f1 = 0; f1 < 2; ++f1) {
                ht[f1]  = __builtin_amdgcn_mfma_f32_16x16x32_f16(w1h[f1], zh, ht[f1],  0, 0, 0);
                htr[f1] = __builtin_amdgcn_mfma_f32_16x16x32_f16(w1l[f1], zh, htr[f1], 0, 0, 0);
                htr[f1] = __builtin_amdgcn_mfma_f32_16x16x32_f16(w1h[f1], zl, htr[f1], 0, 0, 0);
            }
            // D[row=q*4+r][col=l15] = h^T[mid=mt*16+q*4+r][batch=l15]
            // combine scaled acc, bias, tanh, fp16 2-way split, b64 store
            #pragma unroll
            for (int f1 = 0; f1 < 2; ++f1) {
                const int mt = wave * 2 + f1;
                half4 vh, vl;
                #pragma unroll
                for (int r = 0; r < 4; ++r) {
                    const float pre = ht[f1][r] + htr[f1][r] * IRSC + b1v[f1][r];
                    const float e = __expf(2.f * pre);        // tanh
                    const float h = 1.f - 2.f / (e + 1.f);
                    const _Float16 hh = (_Float16)h;
                    vh[r] = hh;
                    vl[r] = (_Float16)((h - (float)hh) * RSC);
                }
                *(half4*)&sHh[l15][mt * 16 + q * 4] = vh;
                *(half4*)&sHl[l15][mt * 16 + q * 4] = vl;
            }
            __syncthreads();

            // ---------- phase 2 (MFMA): G = h @ W2 + b2, K=128 ----------
            floatx4 g[3], gr[3];
            #pragma unroll
            for (int f = 0; f < 3; ++f) {
                g[f]  = floatx4{0.f, 0.f, 0.f, 0.f};
                gr[f] = floatx4{0.f, 0.f, 0.f, 0.f};
            }
            #pragma unroll
            for (int ks = 0; ks < 4; ++ks) {
                const half8 ah = *(const half8*)&sHh[l15][ks * 32 + q * 8];
                const half8 al = *(const half8*)&sHl[l15][ks * 32 + q * 8];
                #pragma unroll
                for (int f = 0; f < 3; ++f) {
                    g[f]  = __builtin_amdgcn_mfma_f32_16x16x32_f16(ah, w2h[f][ks], g[f],  0, 0, 0);
                    gr[f] = __builtin_amdgcn_mfma_f32_16x16x32_f16(al, w2h[f][ks], gr[f], 0, 0, 0);
                    gr[f] = __builtin_amdgcn_mfma_f32_16x16x32_f16(ah, w2l[f][ks], gr[f], 0, 0, 0);
                }
            }
            // store in [b][i*GIS+o] layout: addr = batch*GBS + (n%6)*GIS + n/6
            #pragma unroll
            for (int f = 0; f < 3; ++f) {
                #pragma unroll
                for (int r = 0; r < 4; ++r)
                    sGf[(q * 4 + r) * GBS + gofs[f]] = g[f][r] + gr[f][r] * IRSC + b2v[f];
            }
            __syncthreads();

            // ---------- contraction k = G . dx, RK4 update, z-split ----------
            const int dsel = (s == 0) ? 0 : ((s == 3) ? 2 : 1);
            const float ws = (s == 0 || s == 3) ? dt * (1.f / 6.f) : dt * (1.f / 3.f);
            const int o  = tid & 31;
            const int bA = tid >> 5, bB = bA + 8;     // jj=0 / jj=1 batches
            #pragma unroll
            for (int jj = 0; jj < 2; ++jj) {
                const int b = (jj == 0) ? bA : bB;
                float k = 0.f;
                #pragma unroll
                for (int i = 0; i < 6; ++i)
                    k += sGf[b * GBS + i * GIS + o] * sDx[dsel][b][i];
                const float zan = za[jj] + ws * k;
                za[jj] = zan;
                float zc;
                if (s < 3) {
                    zc = zb[jj] + ((s == 2) ? dt : 0.5f * dt) * k;
                } else {
                    zb[jj] = zan;
                    zc = zan;
                }
                // fp16 2-way split of next-stage z (phase-1 B operand)
                const _Float16 zh0 = (_Float16)zc;
                sZh[b][o] = zh0;
                sZl[b][o] = (_Float16)((zc - (float)zh0) * RSC);
            }
            __syncthreads();
        }
    }

    // ---------- readout: out = zT @ Wl + bl ----------
    {
        const int o = tid & 31, bA = tid >> 5;
        sFin[bA][o]     = zb[0];
        sFin[bA + 8][o] = zb[1];
    }
    __syncthreads();
    if (tid < NB * CIN) {
        const int bb = tid / CIN, c = tid - bb * CIN;
        float acc = blg[c];
        #pragma unroll
        for (int o = 0; o < H; ++o) acc += sFin[bb][o] * Wlg[o * CIN + c];
        out[(size_t)(b0 + bb) * CIN + c] = acc;
    }
}

extern "C" void kernel_launch(void* const* d_in, const int* in_sizes, int n_in,
                              void* d_out, int out_size, void* d_ws, size_t ws_size,
                              hipStream_t stream) {
    const float* times = (const float*)d_in[0];
    // d_in[1] = coeff_a: unused by the reference vector field
    const float* cb = (const float*)d_in[2];
    const float* cc = (const float*)d_in[3];
    const float* cd = (const float*)d_in[4];
    const float* W1 = (const float*)d_in[5];
    const float* b1 = (const float*)d_in[6];
    const float* W2 = (const float*)d_in[7];
    const float* b2 = (const float*)d_in[8];
    const float* Wl = (const float*)d_in[9];
    const float* bl = (const float*)d_in[10];
    float* out = (float*)d_out;

    hipLaunchKernelGGL(cde_hybrid_kernel, dim3(B_TOT / NB), dim3(WG), 0, stream,
                       times, cb, cc, cd, W1, b1, W2, b2, Wl, bl, out);
}

// Round 6
// 2196.456 us; speedup vs baseline: 1.7477x; 1.0449x over previous
//
#include <hip/hip_runtime.h>

// NeuralCDE RK4 — R11: R10 + G/dx-path LDS re-layout (LDS issue-count cut).
// Model: kernel is LDS-issue-serialization-bound (54 issues/wave-stage through
// the per-CU LDS pipe; bytes are 3x under the BW floor). Changes:
//   - sGf -> plain [b][n] layout, b-stride NST=50 (even):
//       stores: bank = 8q+18r+l15+c -> every bank exactly 2x (2-way = free)
//       reads:  n=6o..6o+5 contiguous -> 3x ds_read_b64 per (b,o) pair
//               (was 12 b32); 8B-aligned since NST even; o/o+16 alias 2-way
//   - dx -> registers via b128+b64 per batch (4 issues, was 12 b32)
//   - gofs de-permute deleted (plain n indexing)
// Per-wave-stage LDS issues: 54 -> 40 (-26%), G-path conflict-free by
// construction. Contraction FMA order (i ascending) preserved -> bit-identical.
// Everything else = R10 (fp16 2-way split MFMA, 3 barriers/stage, reg za/zb).
// MFMA conventions = HW-verified m89/m120 mappings:
//   A[m=lane&15][k=quad*8+j], B[k=quad*8+j][n=lane&15], D[row=quad*4+r][col=lane&15]

typedef _Float16 half8 __attribute__((ext_vector_type(8)));
typedef _Float16 half4 __attribute__((ext_vector_type(4)));
typedef float floatx4 __attribute__((ext_vector_type(4)));
typedef float floatx2 __attribute__((ext_vector_type(2)));

constexpr int B_TOT  = 8192;
constexpr int L      = 256;
constexpr int CIN    = 6;
constexpr int H      = 32;
constexpr int MID    = 128;
constexpr int NSTEPS = L - 1;   // 255
constexpr int NB     = 16;      // batches per WG (one 16-row M tile)
constexpr int WG     = 256;     // 4 waves
// grid = B_TOT/NB = 512 -> 2 blocks/CU

constexpr int HP  = 152;   // h split row stride (halves): 76 dw === 12 mod 32
constexpr int ZSP = 72;    // z split row stride (halves): 36 dw === 4 mod 32
constexpr int NST = 50;    // sGf b-stride (floats, EVEN): stores 2-way, b64 reads aligned
constexpr int ZP  = 33;    // final-state rows (odd)

constexpr float RSC  = 2048.f;        // 2^11 residual scale
constexpr float IRSC = 1.f / 2048.f;  // exact power of 2

__global__ __launch_bounds__(WG, 1)
void cde_hybrid_kernel(const float* __restrict__ times,
                       const float* __restrict__ coeff_b,
                       const float* __restrict__ coeff_c,
                       const float* __restrict__ coeff_d,
                       const float* __restrict__ W1g,
                       const float* __restrict__ b1g,
                       const float* __restrict__ W2g,
                       const float* __restrict__ b2g,
                       const float* __restrict__ Wlg,
                       const float* __restrict__ blg,
                       float* __restrict__ out)
{
    __shared__ __align__(16) _Float16 sHh[NB][HP], sHl[NB][HP];   // 9.5 KB
    __shared__ __align__(16) float sGf[NB * NST];                 // 3.2 KB
    __shared__ __align__(16) _Float16 sZh[NB][ZSP], sZl[NB][ZSP]; // 4.5 KB
    __shared__ __align__(16) float sDx[3][NB][8];                 // 1.5 KB
    __shared__ float sFin[NB][ZP];                                // 2.1 KB

    const int tid  = threadIdx.x;
    const int lane = tid & 63;
    const int wave = tid >> 6;      // 0..3
    const int l15  = lane & 15;
    const int q    = lane >> 4;     // 0..3
    const int b0   = blockIdx.x * NB;

    // ---- one-time: W2 fragments -> registers (fp16 hi + scaled-res), phase-2 B ----
    // wave covers N-tiles {3*wave .. 3*wave+2}; K covered by ks=0..3.
    half8 w2h[3][4], w2l[3][4];
    float b2v[3];
    #pragma unroll
    for (int f = 0; f < 3; ++f) {
        const int n = (wave * 3 + f) * 16 + l15;
        b2v[f] = b2g[n];
        #pragma unroll
        for (int ks = 0; ks < 4; ++ks) {
            #pragma unroll
            for (int j = 0; j < 8; ++j) {
                const float w = W2g[(ks * 32 + q * 8 + j) * (H * CIN) + n];
                const _Float16 hh = (_Float16)w;
                w2h[f][ks][j] = hh;
                w2l[f][ks][j] = (_Float16)((w - (float)hh) * RSC);
            }
        }
    }

    // ---- one-time: W1^T fragments -> registers (fp16 hi + scaled-res), phase-1 A ----
    half8 w1h[2], w1l[2];
    float b1v[2][4];
    #pragma unroll
    for (int f1 = 0; f1 < 2; ++f1) {
        const int mt = wave * 2 + f1;
        #pragma unroll
        for (int j = 0; j < 8; ++j) {
            const float w = W1g[(q * 8 + j) * MID + mt * 16 + l15];
            const _Float16 hh = (_Float16)w;
            w1h[f1][j] = hh;
            w1l[f1][j] = (_Float16)((w - (float)hh) * RSC);
        }
        #pragma unroll
        for (int r = 0; r < 4; ++r)
            b1v[f1][r] = b1g[mt * 16 + q * 4 + r];   // D row = mid = mt*16+q*4+r
    }

    // ---- one-time init: z splits to zero; RK4 state in registers ----
    // thread owns (b,o): o = tid&31, batches bA = tid>>5 and bB = bA+8
    float za[2] = {0.f, 0.f};
    float zb[2] = {0.f, 0.f};
    for (int i = tid; i < NB * ZSP; i += WG) {
        (&sZh[0][0])[i] = (_Float16)0.f; (&sZl[0][0])[i] = (_Float16)0.f;
    }
    __syncthreads();

    for (int t = 0; t < NSTEPS; ++t) {
        const float dt = times[t + 1] - times[t];
        if (tid < NB * CIN) {
            const int bb = tid / CIN, ii = tid - bb * CIN;
            const size_t off = ((size_t)(b0 + bb) * NSTEPS + t) * CIN + ii;
            const float vb = coeff_b[off], vc = coeff_c[off], vd = coeff_d[off];
            const float f1 = 0.5f * dt;
            sDx[0][bb][ii] = vb;                              // dX(0)
            sDx[1][bb][ii] = vb + vc * f1 + vd * f1 * f1;     // dX(dt/2)
            sDx[2][bb][ii] = vb + vc * dt + vd * dt * dt;     // dX(dt)
        }
        __syncthreads();

        #pragma unroll 1
        for (int s = 0; s < 4; ++s) {
            // ---------- phase 1 (MFMA): h^T = tanh(W1^T @ z^T + b1) ----------
            // B-frag: B[k=q*8+j][n=l15] = z[l15][q*8+j]  (b128 row read)
            const half8 zh = *(const half8*)&sZh[l15][q * 8];
            const half8 zl = *(const half8*)&sZl[l15][q * 8];
            floatx4 ht[2], htr[2];
            #pragma unroll
            for (int f1 = 0; f1 < 2; ++f1) {
                ht[f1]  = floatx4{0.f, 0.f, 0.f, 0.f};
                htr[f1] = floatx4{0.f, 0.f, 0.f, 0.f};
            }
            #pragma unroll
            for (int f1 = 0; f1 < 2; ++f1) {
                ht[f1]  = __builtin_amdgcn_mfma_f32_16x16x32_f16(w1h[f1], zh, ht[f1],  0, 0, 0);
                htr[f1] = __builtin_amdgcn_mfma_f32_16x16x32_f16(w1l[f1], zh, htr[f1], 0, 0, 0);
                htr[f1] = __builtin_amdgcn_mfma_f32_16x16x32_f16(w1h[f1], zl, htr[f1], 0, 0, 0);
            }
            // D[row=q*4+r][col=l15] = h^T[mid=mt*16+q*4+r][batch=l15]
            // combine scaled acc, bias, tanh, fp16 2-way split, b64 store
            #pragma unroll
            for (int f1 = 0; f1 < 2; ++f1) {
                const int mt = wave * 2 + f1;
                half4 vh, vl;
                #pragma unroll
                for (int r = 0; r < 4; ++r) {
                    const float pre = ht[f1][r] + htr[f1][r] * IRSC + b1v[f1][r];
                    const float e = __expf(2.f * pre);        // tanh
                    const float h = 1.f - 2.f / (e + 1.f);
                    const _Float16 hh = (_Float16)h;
                    vh[r] = hh;
                    vl[r] = (_Float16)((h - (float)hh) * RSC);
                }
                *(half4*)&sHh[l15][mt * 16 + q * 4] = vh;
                *(half4*)&sHl[l15][mt * 16 + q * 4] = vl;
            }
            __syncthreads();

            // ---------- phase 2 (MFMA): G = h @ W2 + b2, K=128 ----------
            floatx4 g[3], gr[3];
            #pragma unroll
            for (int f = 0; f < 3; ++f) {
                g[f]  = floatx4{0.f, 0.f, 0.f, 0.f};
                gr[f] = floatx4{0.f, 0.f, 0.f, 0.f};
            }
            #pragma unroll
            for (int ks = 0; ks < 4; ++ks) {
                const half8 ah = *(const half8*)&sHh[l15][ks * 32 + q * 8];
                const half8 al = *(const half8*)&sHl[l15][ks * 32 + q * 8];
                #pragma unroll
                for (int f = 0; f < 3; ++f) {
                    g[f]  = __builtin_amdgcn_mfma_f32_16x16x32_f16(ah, w2h[f][ks], g[f],  0, 0, 0);
                    gr[f] = __builtin_amdgcn_mfma_f32_16x16x32_f16(al, w2h[f][ks], gr[f], 0, 0, 0);
                    gr[f] = __builtin_amdgcn_mfma_f32_16x16x32_f16(ah, w2l[f][ks], gr[f], 0, 0, 0);
                }
            }
            // store plain [b][n]: addr = (q*4+r)*NST + (wave*3+f)*16 + l15
            // bank = 8q + 18r + l15 + c mod 32 -> exactly 2 lanes/bank (free)
            #pragma unroll
            for (int f = 0; f < 3; ++f) {
                const int n = (wave * 3 + f) * 16 + l15;
                #pragma unroll
                for (int r = 0; r < 4; ++r)
                    sGf[(q * 4 + r) * NST + n] = g[f][r] + gr[f][r] * IRSC + b2v[f];
            }
            __syncthreads();

            // ---------- contraction k = G . dx, RK4 update, z-split ----------
            const int dsel = (s == 0) ? 0 : ((s == 3) ? 2 : 1);
            const float ws = (s == 0 || s == 3) ? dt * (1.f / 6.f) : dt * (1.f / 3.f);
            const int o  = tid & 31;
            const int bA = tid >> 5, bB = bA + 8;     // jj=0 / jj=1 batches
            // dx -> registers (b128 + b64 per batch; 4 LDS issues total)
            const floatx4 dA4 = *(const floatx4*)&sDx[dsel][bA][0];
            const floatx2 dA2 = *(const floatx2*)&sDx[dsel][bA][4];
            const floatx4 dB4 = *(const floatx4*)&sDx[dsel][bB][0];
            const floatx2 dB2 = *(const floatx2*)&sDx[dsel][bB][4];
            #pragma unroll
            for (int jj = 0; jj < 2; ++jj) {
                const int b = (jj == 0) ? bA : bB;
                // G reads: 3 x b64, n = 6o+{0,1},{2,3},{4,5} (contiguous, aligned)
                const floatx2 g01 = *(const floatx2*)&sGf[b * NST + 6 * o];
                const floatx2 g23 = *(const floatx2*)&sGf[b * NST + 6 * o + 2];
                const floatx2 g45 = *(const floatx2*)&sGf[b * NST + 6 * o + 4];
                float k = 0.f;
                k += g01[0] * ((jj == 0) ? dA4[0] : dB4[0]);
                k += g01[1] * ((jj == 0) ? dA4[1] : dB4[1]);
                k += g23[0] * ((jj == 0) ? dA4[2] : dB4[2]);
                k += g23[1] * ((jj == 0) ? dA4[3] : dB4[3]);
                k += g45[0] * ((jj == 0) ? dA2[0] : dB2[0]);
                k += g45[1] * ((jj == 0) ? dA2[1] : dB2[1]);
                const float zan = za[jj] + ws * k;
                za[jj] = zan;
                float zc;
                if (s < 3) {
                    zc = zb[jj] + ((s == 2) ? dt : 0.5f * dt) * k;
                } else {
                    zb[jj] = zan;
                    zc = zan;
                }
                // fp16 2-way split of next-stage z (phase-1 B operand)
                const _Float16 zh0 = (_Float16)zc;
                sZh[b][o] = zh0;
                sZl[b][o] = (_Float16)((zc - (float)zh0) * RSC);
            }
            __syncthreads();
        }
    }

    // ---------- readout: out = zT @ Wl + bl ----------
    {
        const int o = tid & 31, bA = tid >> 5;
        sFin[bA][o]     = zb[0];
        sFin[bA + 8][o] = zb[1];
    }
    __syncthreads();
    if (tid < NB * CIN) {
        const int bb = tid / CIN, c = tid - bb * CIN;
        float acc = blg[c];
        #pragma unroll
        for (int o = 0; o < H; ++o) acc += sFin[bb][o] * Wlg[o * CIN + c];
        out[(size_t)(b0 + bb) * CIN + c] = acc;
    }
}

extern "C" void kernel_launch(void* const* d_in, const int* in_sizes, int n_in,
                              void* d_out, int out_size, void* d_ws, size_t ws_size,
                              hipStream_t stream) {
    const float* times = (const float*)d_in[0];
    // d_in[1] = coeff_a: unused by the reference vector field
    const float* cb = (const float*)d_in[2];
    const float* cc = (const float*)d_in[3];
    const float* cd = (const float*)d_in[4];
    const float* W1 = (const float*)d_in[5];
    const float* b1 = (const float*)d_in[6];
    const float* W2 = (const float*)d_in[7];
    const float* b2 = (const float*)d_in[8];
    const float* Wl = (const float*)d_in[9];
    const float* bl = (const float*)d_in[10];
    float* out = (float*)d_out;

    hipLaunchKernelGGL(cde_hybrid_kernel, dim3(B_TOT / NB), dim3(WG), 0, stream,
                       times, cb, cc, cd, W1, b1, W2, b2, Wl, bl, out);
}